// Round 1
// 244.908 us; speedup vs baseline: 1.0194x; 1.0194x over previous
//
#include <hip/hip_runtime.h>
#include <math.h>

// Problem constants
#define CH   64
#define FD   128
#define HS   64
#define FS   128
#define NB   8
#define NCTX 3

// workspace layout (float offsets) — only A-frags + bq used now
// (WS_QT/WS_VAL/WS_L3 regions retired: qt/val/l3 live in LDS inside fused kernel)
#define WS_BQ   4227072                 // bq[64]
#define WS_AVH  4227136                 // conv A frags hi: [2][72][64][8] shorts
#define WS_AQH  4264000                 // qt A frags hi  : [2][8][64][8] shorts
#define WS_AQL  4268096
#define WS_AKH  4272192                 // key A frags
#define WS_AKL  4276288

typedef short  s16x8  __attribute__((ext_vector_type(8)));
typedef float  f32x16 __attribute__((ext_vector_type(16)));

__device__ inline unsigned short bf16_rne(float x) {
  unsigned u = __float_as_uint(x);
  u += 0x7FFFu + ((u >> 16) & 1u);
  return (unsigned short)(u >> 16);
}
__device__ inline void split2(float x, unsigned short& h, unsigned short& l) {
  h = bf16_rne(x);
  l = bf16_rne(x - __uint_as_float((unsigned)h << 16));
}

// ---------------------------------------------------------------------------
// afrag_prep: MFMA A-fragments (conv hi; qt/key hi+lo) + bq. 45 blocks.
// (unchanged)
// ---------------------------------------------------------------------------
__global__ __launch_bounds__(256) void afrag_prep(
    const float* __restrict__ Wc, const float* __restrict__ Wf,
    const float* __restrict__ bf, const float* __restrict__ Wk,
    const float* __restrict__ Vw, float* __restrict__ ws) {
  int id = blockIdx.x * 256 + threadIdx.x;
  unsigned short* avh = (unsigned short*)(ws + WS_AVH);
  unsigned short* aqh = (unsigned short*)(ws + WS_AQH);
  unsigned short* aql = (unsigned short*)(ws + WS_AQL);
  unsigned short* akh = (unsigned short*)(ws + WS_AKH);
  unsigned short* akl = (unsigned short*)(ws + WS_AKL);

  if (id < 9216) {                       // conv frags: hi only
    int tile = id / 4608, rem = id % 4608;
    int q = rem >> 6, l = rem & 63;
    int am = l & 31, kh = l >> 5;
    int c = tile * 32 + am, tap = q >> 3, kf = q & 7;
#pragma unroll
    for (int j = 0; j < 8; ++j) {
      int f = kf * 16 + kh * 8 + j;
      avh[id * 8 + j] = bf16_rne(Vw[(c * FD + f) * 9 + tap]);
    }
  } else if (id < 10240) {               // qt: Wq = Wc^T Wf inline
    int i2 = id - 9216;
    int tile = i2 >> 9, rem = i2 & 511;
    int q = rem >> 6, l = rem & 63;
    int am = l & 31, kh = l >> 5;
    int c = tile * 32 + am;
#pragma unroll
    for (int j = 0; j < 8; ++j) {
      int f = q * 16 + kh * 8 + j;
      float acc = 0.f;
      for (int d = 0; d < CH; ++d)
        acc = fmaf(Wc[d * CH + c], Wf[d * FD + f], acc);
      unsigned short h, lo; split2(acc, h, lo);
      aqh[i2 * 8 + j] = h; aql[i2 * 8 + j] = lo;
    }
  } else if (id < 11264) {               // keys: Wk direct
    int i3 = id - 10240;
    int tile = i3 >> 9, rem = i3 & 511;
    int q = rem >> 6, l = rem & 63;
    int am = l & 31, kh = l >> 5;
    int c = tile * 32 + am;
#pragma unroll
    for (int j = 0; j < 8; ++j) {
      int f = q * 16 + kh * 8 + j;
      unsigned short h, lo; split2(Wk[c * FD + f], h, lo);
      akh[i3 * 8 + j] = h; akl[i3 * 8 + j] = lo;
    }
  } else if (id < 11328) {               // bq = Wc^T bf
    int c = id - 11264;
    float acc = 0.f;
    for (int d = 0; d < CH; ++d) acc = fmaf(Wc[d * CH + c], bf[d], acc);
    ws[WS_BQ + c] = acc;
  }
}

// ---------------------------------------------------------------------------
// fused_kernel: one block per (b,y half-res row), 512 threads.
// Phase A (= old half_fused): stage 3 m-rows to LDS HI, waves 0-3 conv,
//   waves 4-7 qt+keys (hi/lo split) + l3 — results land in LDS (union over HI).
// Phase B (= old fullres): two output rows 2y,2y+1; single HBM pass over ctx
//   held in registers across softmax; logit c-reduce via shfl + 6KB wpart LDS.
// Eliminates the qt/val/l3 HBM round-trip (~50 MB) and one kernel launch.
// ---------------------------------------------------------------------------
__global__ __launch_bounds__(512) void fused_kernel(
    const float* __restrict__ m, const float* __restrict__ Vb,
    const float* __restrict__ bk, const float* __restrict__ ctx,
    float* __restrict__ out, const float* __restrict__ ws) {
  const int b = blockIdx.x >> 6, y = blockIdx.x & 63;
  const int t = threadIdx.x, lane = t & 63;
  const int wave = __builtin_amdgcn_readfirstlane(t >> 6);
  const int am = lane & 31, kh = lane >> 5;

  // HI (50688 B) overlaid with phase-B data (39168 B); HI is dead after B2.
  __shared__ __align__(16) union {
    short HI[3][8][66][2][8];            // [row 0..2][kf][col+pad][kh][8f]
    struct {
      float  QT[CH * HS];                // [c][x2] row y, with bq
      float  VAL[CH * HS];               // [c][x2] row y, with Vb
      float4 wpart[2][4][3][16];         // [u][wave-in-unit][n][quad]
      float  L3row[HS];                  // l3 logits, row y
    } p;
  } U;
  __shared__ float l3red[2][64];

  // ---- zero x-borders (cols 0 and 65) ----
  if (t < 96) {
    int row = t / 32, kf = (t >> 2) & 7, khh = (t >> 1) & 1, col = (t & 1) * 65;
    s16x8 z;
#pragma unroll
    for (int j = 0; j < 8; ++j) z[j] = 0;
    *(s16x8*)&U.HI[row][kf][col][khh][0] = z;
  }

  // ---- stage hi: 48 wave-tasks (row,kf,kh), 6 per wave; coalesced reads ----
#pragma unroll
  for (int i = 0; i < 6; ++i) {
    const int tk = wave * 6 + i;               // 0..47
    const int row = tk >> 4, kf = (tk >> 1) & 7, khh = tk & 1;
    const int yy = y + row - 1;
    s16x8 hi;
    if (yy >= 0 && yy < HS) {
#pragma unroll
      for (int j = 0; j < 8; ++j) {
        const int f = kf * 16 + khh * 8 + j;
        hi[j] = (short)bf16_rne(m[((b * FD + f) * HS + yy) * HS + lane]);
      }
    } else {
#pragma unroll
      for (int j = 0; j < 8; ++j) hi[j] = 0;
    }
    *(s16x8*)&U.HI[row][kf][lane + 1][khh][0] = hi;
  }
  __syncthreads();                             // B1: HI staged

  // wave roles: waves 0-3 conv, waves 4-7 qt+keys.
  // ct/xh identical to old mapping: conv ct=wave>>1; qt ct=(wave-4)>>1 = (wave>>1)&1
  const int ct = (wave >> 1) & 1;
  const int xh = wave & 1;
  const int x0 = xh * 32, ch0 = ct * 32;

  f32x16 acc, q1, q2, k1, k2;
  float l3part = 0.f;

  if (wave < 4) {
    // ---- conv: tile (ct,xh), all 72 K-chunks, A-hi x B-hi ----
    const unsigned short* avh = (const unsigned short*)(ws + WS_AVH);
#pragma unroll
    for (int i = 0; i < 16; ++i) acc[i] = 0.f;
#pragma unroll 8
    for (int q = 0; q < 72; ++q) {
      const int tap = q >> 3, kf = q & 7;
      const s16x8 ah = *(const s16x8*)(avh + ((ct * 72 + q) * 64 + lane) * 8);
      const s16x8 bh = *(const s16x8*)&U.HI[tap / 3][kf][x0 + am + tap % 3][kh][0];
      acc = __builtin_amdgcn_mfma_f32_32x32x16_bf16(ah, bh, acc, 0, 0, 0);
    }
  } else {
    // ---- qt + keys: K=128, 3-MFMA hi/lo split each ----
    const unsigned short* aqh = (const unsigned short*)(ws + WS_AQH);
    const unsigned short* aql = (const unsigned short*)(ws + WS_AQL);
    const unsigned short* akh = (const unsigned short*)(ws + WS_AKH);
    const unsigned short* akl = (const unsigned short*)(ws + WS_AKL);
#pragma unroll
    for (int i = 0; i < 16; ++i) { q1[i] = 0.f; q2[i] = 0.f; k1[i] = 0.f; k2[i] = 0.f; }
#pragma unroll
    for (int q = 0; q < 8; ++q) {
      const s16x8 bh = *(const s16x8*)&U.HI[1][q][x0 + am + 1][kh][0];
      s16x8 bl;
#pragma unroll
      for (int j = 0; j < 8; ++j) {
        const float mv = m[((b * FD + q * 16 + kh * 8 + j) * HS + y) * HS + x0 + am];
        const float hf = __uint_as_float(((unsigned)(unsigned short)bh[j]) << 16);
        bl[j] = (short)bf16_rne(mv - hf);
      }
      const s16x8 ah = *(const s16x8*)(aqh + ((ct * 8 + q) * 64 + lane) * 8);
      const s16x8 al = *(const s16x8*)(aql + ((ct * 8 + q) * 64 + lane) * 8);
      const s16x8 kah = *(const s16x8*)(akh + ((ct * 8 + q) * 64 + lane) * 8);
      const s16x8 kal = *(const s16x8*)(akl + ((ct * 8 + q) * 64 + lane) * 8);
      q1 = __builtin_amdgcn_mfma_f32_32x32x16_bf16(ah, bh, q1, 0, 0, 0);
      q1 = __builtin_amdgcn_mfma_f32_32x32x16_bf16(al, bh, q1, 0, 0, 0);
      q2 = __builtin_amdgcn_mfma_f32_32x32x16_bf16(ah, bl, q2, 0, 0, 0);
      k1 = __builtin_amdgcn_mfma_f32_32x32x16_bf16(kah, bh, k1, 0, 0, 0);
      k1 = __builtin_amdgcn_mfma_f32_32x32x16_bf16(kal, bh, k1, 0, 0, 0);
      k2 = __builtin_amdgcn_mfma_f32_32x32x16_bf16(kah, bl, k2, 0, 0, 0);
    }
  }
  __syncthreads();                             // B2: all HI reads done

  // ---- spill accumulators to LDS (union region, HI now dead) ----
  if (wave < 4) {
#pragma unroll
    for (int r = 0; r < 16; ++r) {
      const int c = ch0 + (r & 3) + 8 * (r >> 2) + 4 * kh;
      U.p.VAL[c * HS + x0 + am] = acc[r] + Vb[c];
    }
  } else {
#pragma unroll
    for (int r = 0; r < 16; ++r) {
      const int c = ch0 + (r & 3) + 8 * (r >> 2) + 4 * kh;
      const float qvv = q1[r] + q2[r] + ws[WS_BQ + c];
      const float kvv = k1[r] + k2[r] + bk[c];
      U.p.QT[c * HS + x0 + am] = qvv;
      l3part = fmaf(qvv, kvv, l3part);
    }
    if (ct == 1) l3red[xh][lane] = l3part;     // waves 6,7
  }
  __syncthreads();                             // B3: QT/VAL/l3red ready

  // ---- l3 = sum over all 64 ch: waves 4,5 (ct=0) finish ----
  if (wave == 4 || wave == 5) {
    float s = l3part + l3red[xh][lane];
    s += __shfl_xor(s, 32, 64);
    if (kh == 0) U.p.L3row[x0 + am] = s;
  }
  __syncthreads();                             // B4: phase-B inputs ready

  // =======================================================================
  // Phase B: old fullres, rows 2y (unit 0) and 2y+1 (unit 1), x halves looped
  // =======================================================================
  const int u    = t >> 8;                     // output row sub-block
  const int tt   = t & 255;
  const int quad = tt & 15;
  const int cg   = tt >> 4;
  const int wv   = tt >> 6;                    // wave within unit (0..3)
  const int c0   = cg * 4;
  const int hrow = 2 * y + u;
  const int cs = FS * FS, ns = CH * FS * FS;

  float* op = out + (size_t)(b * CH) * FS * FS + (size_t)hrow * FS;
  const float* cb = ctx + (size_t)(b * NCTX * CH) * cs + (size_t)hrow * FS;

#pragma unroll 1
  for (int x2 = 0; x2 < 2; ++x2) {
    const int x = x2 * 64 + quad * 4;
    const int w2 = x >> 1;

    float4 cv[3][4];
    float2 qv[4];
#pragma unroll
    for (int j = 0; j < 4; ++j) {
      const int c = c0 + j;
      cv[0][j] = *(const float4*)(cb + x + c * cs);
      cv[1][j] = *(const float4*)(cb + x + ns + c * cs);
      cv[2][j] = *(const float4*)(cb + x + 2 * ns + c * cs);
      qv[j] = *(const float2*)&U.p.QT[c * HS + w2];
    }

    float4 pl[3];
#pragma unroll
    for (int n = 0; n < 3; ++n) {
      pl[n].x = pl[n].y = pl[n].z = pl[n].w = 0.f;
#pragma unroll
      for (int j = 0; j < 4; ++j) {
        pl[n].x = fmaf(cv[n][j].x, qv[j].x, pl[n].x);
        pl[n].y = fmaf(cv[n][j].y, qv[j].x, pl[n].y);
        pl[n].z = fmaf(cv[n][j].z, qv[j].y, pl[n].z);
        pl[n].w = fmaf(cv[n][j].w, qv[j].y, pl[n].w);
      }
    }

    // in-wave reduce over the wave's 4 c-groups (lanes ^16, ^32)
#pragma unroll
    for (int n = 0; n < 3; ++n) {
      pl[n].x += __shfl_xor(pl[n].x, 16, 64);
      pl[n].y += __shfl_xor(pl[n].y, 16, 64);
      pl[n].z += __shfl_xor(pl[n].z, 16, 64);
      pl[n].w += __shfl_xor(pl[n].w, 16, 64);
      pl[n].x += __shfl_xor(pl[n].x, 32, 64);
      pl[n].y += __shfl_xor(pl[n].y, 32, 64);
      pl[n].z += __shfl_xor(pl[n].z, 32, 64);
      pl[n].w += __shfl_xor(pl[n].w, 32, 64);
    }
    __syncthreads();                           // wpart free (prev iter read)
    if ((lane >> 4) == 0) {
#pragma unroll
      for (int n = 0; n < 3; ++n) U.p.wpart[u][wv][n][quad] = pl[n];
    }
    __syncthreads();                           // wpart ready

    float4 L[3];
#pragma unroll
    for (int n = 0; n < 3; ++n) {
      const float4 p0 = U.p.wpart[u][0][n][quad];
      const float4 p1 = U.p.wpart[u][1][n][quad];
      const float4 p2 = U.p.wpart[u][2][n][quad];
      const float4 p3 = U.p.wpart[u][3][n][quad];
      L[n].x = (p0.x + p1.x) + (p2.x + p3.x);
      L[n].y = (p0.y + p1.y) + (p2.y + p3.y);
      L[n].z = (p0.z + p1.z) + (p2.z + p3.z);
      L[n].w = (p0.w + p1.w) + (p2.w + p3.w);
    }
    const float2 l3v = *(const float2*)&U.p.L3row[w2];

    float A0[4], A1[4], A2[4], A3[4];
    const float* L0p = (const float*)&L[0];
    const float* L1p = (const float*)&L[1];
    const float* L2p = (const float*)&L[2];
#pragma unroll
    for (int k = 0; k < 4; ++k) {
      float L0 = L0p[k], L1 = L1p[k], L2 = L2p[k];
      float L3 = (k < 2) ? l3v.x : l3v.y;
      float mx = fmaxf(fmaxf(L0, L1), fmaxf(L2, L3));
      float e0 = __expf(L0 - mx), e1 = __expf(L1 - mx);
      float e2 = __expf(L2 - mx), e3 = __expf(L3 - mx);
      float inv = 1.f / (e0 + e1 + e2 + e3);
      A0[k] = e0 * inv; A1[k] = e1 * inv; A2[k] = e2 * inv; A3[k] = e3 * inv;
    }

#pragma unroll
    for (int j = 0; j < 4; ++j) {
      const int c = c0 + j;
      const float2 vv = *(const float2*)&U.p.VAL[c * HS + w2];
      float4 o;
      o.x = fmaf(A0[0], cv[0][j].x, fmaf(A1[0], cv[1][j].x, fmaf(A2[0], cv[2][j].x, A3[0] * vv.x)));
      o.y = fmaf(A0[1], cv[0][j].y, fmaf(A1[1], cv[1][j].y, fmaf(A2[1], cv[2][j].y, A3[1] * vv.x)));
      o.z = fmaf(A0[2], cv[0][j].z, fmaf(A1[2], cv[1][j].z, fmaf(A2[2], cv[2][j].z, A3[2] * vv.y)));
      o.w = fmaf(A0[3], cv[0][j].w, fmaf(A1[3], cv[1][j].w, fmaf(A2[3], cv[2][j].w, A3[3] * vv.y)));
      *(float4*)(op + x + c * cs) = o;
    }
  }
}

// ---------------------------------------------------------------------------
extern "C" void kernel_launch(void* const* d_in, const int* in_sizes, int n_in,
                              void* d_out, int out_size, void* d_ws, size_t ws_size,
                              hipStream_t stream) {
  const float* ctx = (const float*)d_in[0];
  const float* ms  = (const float*)d_in[1];
  const float* Wc  = (const float*)d_in[2];
  // d_in[3] = bc : cancels in softmax
  const float* Wf  = (const float*)d_in[4];
  const float* bf  = (const float*)d_in[5];
  const float* Wk  = (const float*)d_in[6];
  const float* bk  = (const float*)d_in[7];
  const float* Vw  = (const float*)d_in[8];
  const float* Vb  = (const float*)d_in[9];
  float* ws  = (float*)d_ws;
  float* out = (float*)d_out;

  afrag_prep<<<45, 256, 0, stream>>>(Wc, Wf, bf, Wk, Vw, ws);
  fused_kernel<<<NB * HS, 512, 0, stream>>>(ms, Vb, bk, ctx, out, ws);
}